// Round 9
// baseline (223.323 us; speedup 1.0000x reference)
//
#include <hip/hip_runtime.h>
#include <hip/hip_bf16.h>
#include <cstdint>
#include <cstddef>

// Problem constants
#define B_ 8
#define N_ 2048
#define D_ 256
#define H_ 8
#define HD_ 32
#define LN_EPS 1e-5f
#define QSCALE 0.25506275f  // log2(e)/sqrt(32): folded into Q so p = exp2(q'.k)

typedef __attribute__((ext_vector_type(8))) short short8;
typedef __attribute__((ext_vector_type(4))) float f32x4;
typedef __attribute__((ext_vector_type(16))) float f32x16;

static __device__ __forceinline__ float exp2v(float x) {
#if __has_builtin(__builtin_amdgcn_exp2f)
    return __builtin_amdgcn_exp2f(x);
#else
    float r;
    asm("v_exp_f32 %0, %1" : "=v"(r) : "v"(x));
    return r;
#endif
}

static __device__ __forceinline__ unsigned short f2bf(float f) {
    union { float f; unsigned int u; } v; v.f = f;
    unsigned int r = v.u + 0x7fffu + ((v.u >> 16) & 1u);
    return (unsigned short)(r >> 16);
}

static __device__ __forceinline__ float bf2f(unsigned short u) {
    union { unsigned int u; float f; } v; v.u = ((unsigned int)u) << 16;
    return v.f;
}

static __device__ __forceinline__ unsigned int cvtpk(float lo, float hi) {
    unsigned int d;
    asm("v_cvt_pk_bf16_f32 %0, %1, %2" : "=v"(d) : "v"(lo), "v"(hi));
    return d;
}

// ---------------- prep: x fp32 -> bf16 ----------------
__global__ __launch_bounds__(256) void k_prep_x(const float* __restrict__ x,
                                                unsigned short* __restrict__ xbf, int n4) {
    int i = blockIdx.x * 256 + threadIdx.x;
    if (i >= n4) return;
    float4 v = reinterpret_cast<const float4*>(x)[i];
    ushort4 o;
    o.x = f2bf(v.x); o.y = f2bf(v.y); o.z = f2bf(v.z); o.w = f2bf(v.w);
    reinterpret_cast<ushort4*>(xbf)[i] = o;
}

// ---------------- prep: W fp32 -> bf16 transposed wt[mat][col][k] ----------------
__global__ __launch_bounds__(256) void k_prep_w(const float* __restrict__ w0, const float* __restrict__ w1,
                                                const float* __restrict__ w2, const float* __restrict__ w3,
                                                unsigned short* __restrict__ wt) {
    int c = blockIdx.x, mat = blockIdx.y, k = threadIdx.x;
    const float* w = (mat == 0) ? w0 : (mat == 1) ? w1 : (mat == 2) ? w2 : w3;
    wt[((size_t)(mat * 256 + c)) * 256 + k] = f2bf(w[k * 256 + c]);
}

// ---------------- adjacency -> EXPANDED pair-mask ----------------
// emask[b][t][q][j] (u32): key-tile t (32 keys), pair j covers keys 2j,2j+1 of
// row q: low 16 bits = 0xFFFF if adj[q][32t+2j], high 16 = 0xFFFF if ..2j+1.
// k_attn ANDs these directly onto packed bf16 P pairs (1 VALU op / 2 elements).
// Ballot-free: each lane expands its own int4 (4 cols = 2 pairs -> uint2).
// Thread covers 4 rows (batched loads for MLP). 201MB streamed -> HBM-bound.
__global__ __launch_bounds__(256) void k_memask(const int* __restrict__ adj,
                                                unsigned int* __restrict__ emask) {
    int g = blockIdx.x * 256 + threadIdx.x;
    int w_id = g >> 6, lane = g & 63;
    int row0 = (w_id >> 3) * 4;          // global row = b*2048 + n
    int b = row0 >> 11, n0 = row0 & 2047;
    int w = (w_id & 7) * 8 + (lane >> 3);   // key-tile 0..63
    int sub = lane & 7;                     // int4 within tile (4 cols)
    const int4* src = reinterpret_cast<const int4*>(adj) + (size_t)row0 * 512 + w * 8 + sub;
    uint2* dst = reinterpret_cast<uint2*>(emask + (((size_t)(b * 64 + w)) * 2048 + n0) * 16) + sub;

    int4 v0 = src[0];
    int4 v1 = src[512];
    int4 v2 = src[1024];
    int4 v3 = src[1536];

    uint2 e0, e1, e2, e3;
    e0.x = (v0.x ? 0xFFFFu : 0u) | (v0.y ? 0xFFFF0000u : 0u);
    e0.y = (v0.z ? 0xFFFFu : 0u) | (v0.w ? 0xFFFF0000u : 0u);
    e1.x = (v1.x ? 0xFFFFu : 0u) | (v1.y ? 0xFFFF0000u : 0u);
    e1.y = (v1.z ? 0xFFFFu : 0u) | (v1.w ? 0xFFFF0000u : 0u);
    e2.x = (v2.x ? 0xFFFFu : 0u) | (v2.y ? 0xFFFF0000u : 0u);
    e2.y = (v2.z ? 0xFFFFu : 0u) | (v2.w ? 0xFFFF0000u : 0u);
    e3.x = (v3.x ? 0xFFFFu : 0u) | (v3.y ? 0xFFFF0000u : 0u);
    e3.y = (v3.z ? 0xFFFFu : 0u) | (v3.w ? 0xFFFF0000u : 0u);
    dst[0] = e0;
    dst[8] = e1;
    dst[16] = e2;
    dst[24] = e3;
}

// ---------------- fused QKV projection GEMM ----------------
// Q row-major [bh][n][hd] (scaled). K,V in MFMA fragment-tile order (per bh,
// tile t = 1024 ush; frag f = 512 ush; slot lane*8): direct 1KB wave loads.
__global__ __launch_bounds__(256) void k_qkv(const unsigned short* __restrict__ xbf,
                                             const unsigned short* __restrict__ wt,
                                             const float* __restrict__ bq, const float* __restrict__ bk,
                                             const float* __restrict__ bv,
                                             unsigned short* __restrict__ Qb, unsigned short* __restrict__ Ks,
                                             unsigned short* __restrict__ Vs) {
    int mat = blockIdx.y;
    int lane = threadIdx.x & 63;
    int wv = threadIdx.x >> 6;
    int row0 = blockIdx.x * 64 + wv * 16;
    int l15 = lane & 15, lg = lane >> 4;
    const float* bias = (mat == 0) ? bq : (mat == 1) ? bk : bv;
    const float qs = (mat == 0) ? QSCALE : 1.0f;
    const unsigned short* wm = wt + (size_t)mat * 65536;

    short8 af[8];
    const unsigned short* xrow = xbf + (size_t)(row0 + l15) * 256 + lg * 8;
#pragma unroll
    for (int kk = 0; kk < 8; ++kk)
        af[kk] = *reinterpret_cast<const short8*>(xrow + kk * 32);

    int b = row0 >> 11;            // 2048 rows per batch; 64-row blocks never cross
    int nbase = (row0 & 2047) + lg * 4;

    for (int ci = 0; ci < 16; ++ci) {
        const unsigned short* wrow = wm + (size_t)(ci * 16 + l15) * 256 + lg * 8;
        f32x4 acc = {0.f, 0.f, 0.f, 0.f};
#pragma unroll
        for (int kk = 0; kk < 8; ++kk) {
            short8 bfg = *reinterpret_cast<const short8*>(wrow + kk * 32);
            acc = __builtin_amdgcn_mfma_f32_16x16x32_bf16(af[kk], bfg, acc, 0, 0, 0);
        }
        int col = ci * 16 + l15;
        float bcol = bias[col];
        int h = col >> 5, hd = col & 31;
        size_t bh64 = (size_t)(b * 8 + h) * 65536;
        if (mat == 0) {
#pragma unroll
            for (int r = 0; r < 4; ++r)
                Qb[bh64 + (size_t)(nbase + r) * 32 + hd] = f2bf((acc[r] + bcol) * qs);
        } else if (mat == 1) {
#pragma unroll
            for (int r = 0; r < 4; ++r) {
                int n = nbase + r;
                size_t off = bh64 + (size_t)(n >> 5) * 1024 + (hd >> 4) * 512
                           + (((hd >> 3) & 1) * 32 + (n & 31)) * 8 + (hd & 7);
                Ks[off] = f2bf(acc[r] + bcol);
            }
        } else {
            int posb = nbase & 31;
            size_t off = bh64 + (size_t)(nbase >> 5) * 1024 + (posb >> 4) * 512
                       + ((((posb >> 3) & 1) * 32 + hd)) * 8 + (posb & 7);
            ushort4 o;
            o.x = f2bf(acc[0] + bcol); o.y = f2bf(acc[1] + bcol);
            o.z = f2bf(acc[2] + bcol); o.w = f2bf(acc[3] + bcol);
            *reinterpret_cast<ushort4*>(Vs + off) = o;
        }
    }
}

// ---------------- masked attention ----------------
// Direct-from-L2 (no LDS, no barriers). blk: b = blk&7 (XCD), hg = (blk>>3)&1,
// q0 = (blk>>4)*32; 4 waves = 4 heads. Per 32-key tile: 4x 1KB K/V frag loads,
// 4x uint2 expanded-mask loads; S^T = mfma(K,Q); p = exp2(s) packed to bf16
// then masked with ONE v_and per pair; permlane32_swap -> PV B-frag;
// att^T += mfma(V,P); denominator via ones-MFMA.
__global__ __launch_bounds__(256, 4) void k_attn(const unsigned short* __restrict__ Qb,
                                                 const unsigned short* __restrict__ Ks,
                                                 const unsigned short* __restrict__ Vs,
                                                 const unsigned int* __restrict__ emask,
                                                 unsigned short* __restrict__ att) {
    int tid = threadIdx.x;
    int lane = tid & 63, wv = tid >> 6;
    int l31 = lane & 31, hi = lane >> 5;
    int b = blockIdx.x & 7;
    int hg = (blockIdx.x >> 3) & 1;
    int q0 = (blockIdx.x >> 4) * 32;
    int head = hg * 4 + wv;
    int bh = b * 8 + head;

    const unsigned short* gK = Ks + (size_t)bh * 65536 + (size_t)lane * 8;
    const unsigned short* gV = Vs + (size_t)bh * 65536 + (size_t)lane * 8;
    const unsigned short* Qh = Qb + (size_t)bh * 65536;
    const uint2* emk = reinterpret_cast<const uint2*>(
                           emask + ((size_t)(b * 64) * 2048 + q0 + l31) * 16) + hi;

    short8 qf0 = *reinterpret_cast<const short8*>(Qh + (size_t)(q0 + l31) * 32 + hi * 8);
    short8 qf1 = *reinterpret_cast<const short8*>(Qh + (size_t)(q0 + l31) * 32 + hi * 8 + 16);

    const f32x16 fz = {0.f,0.f,0.f,0.f,0.f,0.f,0.f,0.f,0.f,0.f,0.f,0.f,0.f,0.f,0.f,0.f};
    const short8 onesf = {0x3F80, 0x3F80, 0x3F80, 0x3F80, 0x3F80, 0x3F80, 0x3F80, 0x3F80};
    f32x16 attacc = fz;
    f32x16 onesacc = fz;

#pragma unroll 2
    for (int t = 0; t < 64; ++t) {
        short8 kf0 = *reinterpret_cast<const short8*>(gK + (size_t)t * 1024);
        short8 kf1 = *reinterpret_cast<const short8*>(gK + (size_t)t * 1024 + 512);
        short8 vf0 = *reinterpret_cast<const short8*>(gV + (size_t)t * 1024);
        short8 vf1 = *reinterpret_cast<const short8*>(gV + (size_t)t * 1024 + 512);
        uint2 m0 = emk[(size_t)t * 16384];
        uint2 m1 = emk[(size_t)t * 16384 + 2];
        uint2 m2 = emk[(size_t)t * 16384 + 4];
        uint2 m3 = emk[(size_t)t * 16384 + 6];

        __builtin_amdgcn_s_setprio(1);
        f32x16 s = __builtin_amdgcn_mfma_f32_32x32x16_bf16(kf0, qf0, fz, 0, 0, 0);
        s = __builtin_amdgcn_mfma_f32_32x32x16_bf16(kf1, qf1, s, 0, 0, 0);
        __builtin_amdgcn_s_setprio(0);

        unsigned int pd[4][2];
        pd[0][0] = cvtpk(exp2v(s[0]),  exp2v(s[1]))  & m0.x;
        pd[0][1] = cvtpk(exp2v(s[2]),  exp2v(s[3]))  & m0.y;
        pd[1][0] = cvtpk(exp2v(s[4]),  exp2v(s[5]))  & m1.x;
        pd[1][1] = cvtpk(exp2v(s[6]),  exp2v(s[7]))  & m1.y;
        pd[2][0] = cvtpk(exp2v(s[8]),  exp2v(s[9]))  & m2.x;
        pd[2][1] = cvtpk(exp2v(s[10]), exp2v(s[11])) & m2.y;
        pd[3][0] = cvtpk(exp2v(s[12]), exp2v(s[13])) & m3.x;
        pd[3][1] = cvtpk(exp2v(s[14]), exp2v(s[15])) & m3.y;

        asm("v_permlane32_swap_b32 %0, %1" : "+v"(pd[0][0]), "+v"(pd[1][0]));
        asm("v_permlane32_swap_b32 %0, %1" : "+v"(pd[0][1]), "+v"(pd[1][1]));
        asm("v_permlane32_swap_b32 %0, %1" : "+v"(pd[2][0]), "+v"(pd[3][0]));
        asm("v_permlane32_swap_b32 %0, %1" : "+v"(pd[2][1]), "+v"(pd[3][1]));

        union { short8 s8; unsigned int u[4]; } bf0, bf1;
        bf0.u[0] = pd[0][0]; bf0.u[1] = pd[0][1]; bf0.u[2] = pd[1][0]; bf0.u[3] = pd[1][1];
        bf1.u[0] = pd[2][0]; bf1.u[1] = pd[2][1]; bf1.u[2] = pd[3][0]; bf1.u[3] = pd[3][1];

        __builtin_amdgcn_s_setprio(1);
        attacc = __builtin_amdgcn_mfma_f32_32x32x16_bf16(vf0, bf0.s8, attacc, 0, 0, 0);
        attacc = __builtin_amdgcn_mfma_f32_32x32x16_bf16(vf1, bf1.s8, attacc, 0, 0, 0);
        onesacc = __builtin_amdgcn_mfma_f32_32x32x16_bf16(onesf, bf0.s8, onesacc, 0, 0, 0);
        onesacc = __builtin_amdgcn_mfma_f32_32x32x16_bf16(onesf, bf1.s8, onesacc, 0, 0, 0);
        __builtin_amdgcn_s_setprio(0);
    }

    float rcp = 1.f / onesacc[0];   // every reg holds sum_k P[k][q=l31]

    unsigned short* arow = att + ((size_t)b * N_ + q0 + l31) * D_ + head * HD_;
#pragma unroll
    for (int g = 0; g < 4; ++g) {
        ushort4 o;
        o.x = f2bf(attacc[4 * g + 0] * rcp);
        o.y = f2bf(attacc[4 * g + 1] * rcp);
        o.z = f2bf(attacc[4 * g + 2] * rcp);
        o.w = f2bf(attacc[4 * g + 3] * rcp);
        *reinterpret_cast<ushort4*>(arow + 8 * g + 4 * hi) = o;
    }
}

// ---------------- out projection + residual + LayerNorm ----------------
__global__ __launch_bounds__(256) void k_outln(const unsigned short* __restrict__ att,
                                               const unsigned short* __restrict__ wot,
                                               const float* __restrict__ bo,
                                               const unsigned short* __restrict__ xbf,
                                               const float* __restrict__ gamma, const float* __restrict__ beta,
                                               float* __restrict__ out) {
    int lane = threadIdx.x & 63, wv = threadIdx.x >> 6;
    int l15 = lane & 15, lg = lane >> 4;
    int row0 = blockIdx.x * 64 + wv * 16;

    short8 af[8];
    const unsigned short* arow = att + (size_t)(row0 + l15) * 256 + lg * 8;
#pragma unroll
    for (int kk = 0; kk < 8; ++kk)
        af[kk] = *reinterpret_cast<const short8*>(arow + kk * 32);

    float v[16][4];
#pragma unroll
    for (int ci = 0; ci < 16; ++ci) {
        const unsigned short* wrow = wot + (size_t)(ci * 16 + l15) * 256 + lg * 8;
        f32x4 acc = {0.f, 0.f, 0.f, 0.f};
#pragma unroll
        for (int kk = 0; kk < 8; ++kk) {
            short8 bfg = *reinterpret_cast<const short8*>(wrow + kk * 32);
            acc = __builtin_amdgcn_mfma_f32_16x16x32_bf16(af[kk], bfg, acc, 0, 0, 0);
        }
        float bcol = bo[ci * 16 + l15];
#pragma unroll
        for (int r = 0; r < 4; ++r)
            v[ci][r] = acc[r] + bcol + bf2f(xbf[(size_t)(row0 + lg * 4 + r) * 256 + ci * 16 + l15]);
    }

    float sum[4] = {0.f, 0.f, 0.f, 0.f}, sq[4] = {0.f, 0.f, 0.f, 0.f};
#pragma unroll
    for (int ci = 0; ci < 16; ++ci)
#pragma unroll
        for (int r = 0; r < 4; ++r) {
            sum[r] += v[ci][r];
            sq[r] += v[ci][r] * v[ci][r];
        }
#pragma unroll
    for (int d = 1; d < 16; d <<= 1)
#pragma unroll
        for (int r = 0; r < 4; ++r) {
            sum[r] += __shfl_xor(sum[r], d, 64);
            sq[r] += __shfl_xor(sq[r], d, 64);
        }

    float mu[4], rs[4];
#pragma unroll
    for (int r = 0; r < 4; ++r) {
        mu[r] = sum[r] * (1.f / 256.f);
        float var = sq[r] * (1.f / 256.f) - mu[r] * mu[r];
        rs[r] = rsqrtf(var + LN_EPS);
    }

#pragma unroll
    for (int ci = 0; ci < 16; ++ci) {
        float g = gamma[ci * 16 + l15], be = beta[ci * 16 + l15];
#pragma unroll
        for (int r = 0; r < 4; ++r)
            out[(size_t)(row0 + lg * 4 + r) * 256 + ci * 16 + l15] = (v[ci][r] - mu[r]) * rs[r] * g + be;
    }
}

extern "C" void kernel_launch(void* const* d_in, const int* in_sizes, int n_in,
                              void* d_out, int out_size, void* d_ws, size_t ws_size,
                              hipStream_t stream) {
    (void)in_sizes; (void)n_in; (void)out_size; (void)ws_size;
    const float* x     = (const float*)d_in[0];
    const int*   adj   = (const int*)d_in[1];
    const float* Wq    = (const float*)d_in[2];
    const float* bq    = (const float*)d_in[3];
    const float* Wk    = (const float*)d_in[4];
    const float* bk    = (const float*)d_in[5];
    const float* Wv    = (const float*)d_in[6];
    const float* bv    = (const float*)d_in[7];
    const float* Wo    = (const float*)d_in[8];
    const float* bo    = (const float*)d_in[9];
    const float* gamma = (const float*)d_in[10];
    const float* beta  = (const float*)d_in[11];
    float* out = (float*)d_out;

    char* ws = (char*)d_ws;
    unsigned short* xbf = (unsigned short*)ws; ws += (size_t)16384 * 256 * 2;   // 8.4 MB
    unsigned short* wt  = (unsigned short*)ws; ws += (size_t)4 * 256 * 256 * 2; // 0.5 MB (q,k,v,o)
    unsigned short* Qb  = (unsigned short*)ws; ws += (size_t)B_ * H_ * N_ * HD_ * 2; // 8.4 MB
    unsigned short* Ks  = (unsigned short*)ws; ws += (size_t)B_ * H_ * N_ * HD_ * 2;
    unsigned short* Vs  = (unsigned short*)ws; ws += (size_t)B_ * H_ * N_ * HD_ * 2;
    unsigned short* att = (unsigned short*)ws; ws += (size_t)16384 * 256 * 2;
    unsigned int*   emask = (unsigned int*)ws; ws += (size_t)B_ * 64 * N_ * 16 * 4; // 67 MB

    k_prep_x<<<4096, 256, 0, stream>>>(x, xbf, 1048576);
    k_prep_w<<<dim3(256, 4), 256, 0, stream>>>(Wq, Wk, Wv, Wo, wt);
    k_memask<<<8192, 256, 0, stream>>>(adj, emask);
    k_qkv<<<dim3(256, 3), 256, 0, stream>>>(xbf, wt, bq, bk, bv, Qb, Ks, Vs);
    k_attn<<<1024, 256, 0, stream>>>(Qb, Ks, Vs, emask, att);
    k_outln<<<256, 256, 0, stream>>>(att, wt + 3 * 65536, bo, xbf, gamma, beta, out);
}

// Round 10
// 192.958 us; speedup vs baseline: 1.1574x; 1.1574x over previous
//
#include <hip/hip_runtime.h>
#include <hip/hip_bf16.h>
#include <cstdint>
#include <cstddef>

// Problem constants
#define B_ 8
#define N_ 2048
#define D_ 256
#define H_ 8
#define HD_ 32
#define LN_EPS 1e-5f
#define QSCALE 0.25506275f  // log2(e)/sqrt(32): folded into Q so p = exp2(q'.k)

typedef __attribute__((ext_vector_type(8))) short short8;
typedef __attribute__((ext_vector_type(4))) float f32x4;
typedef __attribute__((ext_vector_type(16))) float f32x16;

static __device__ __forceinline__ float exp2v(float x) {
#if __has_builtin(__builtin_amdgcn_exp2f)
    return __builtin_amdgcn_exp2f(x);
#else
    float r;
    asm("v_exp_f32 %0, %1" : "=v"(r) : "v"(x));
    return r;
#endif
}

static __device__ __forceinline__ unsigned short f2bf(float f) {
    union { float f; unsigned int u; } v; v.f = f;
    unsigned int r = v.u + 0x7fffu + ((v.u >> 16) & 1u);
    return (unsigned short)(r >> 16);
}

static __device__ __forceinline__ float bf2f(unsigned short u) {
    union { unsigned int u; float f; } v; v.u = ((unsigned int)u) << 16;
    return v.f;
}

static __device__ __forceinline__ unsigned int cvtpk(float lo, float hi) {
    unsigned int d;
    asm("v_cvt_pk_bf16_f32 %0, %1, %2" : "=v"(d) : "v"(lo), "v"(hi));
    return d;
}

// ---------------- prep: x fp32 -> bf16 ----------------
__global__ __launch_bounds__(256) void k_prep_x(const float* __restrict__ x,
                                                unsigned short* __restrict__ xbf, int n4) {
    int i = blockIdx.x * 256 + threadIdx.x;
    if (i >= n4) return;
    float4 v = reinterpret_cast<const float4*>(x)[i];
    ushort4 o;
    o.x = f2bf(v.x); o.y = f2bf(v.y); o.z = f2bf(v.z); o.w = f2bf(v.w);
    reinterpret_cast<ushort4*>(xbf)[i] = o;
}

// ---------------- prep: W fp32 -> bf16 transposed wt[mat][col][k] ----------------
__global__ __launch_bounds__(256) void k_prep_w(const float* __restrict__ w0, const float* __restrict__ w1,
                                                const float* __restrict__ w2, const float* __restrict__ w3,
                                                unsigned short* __restrict__ wt) {
    int c = blockIdx.x, mat = blockIdx.y, k = threadIdx.x;
    const float* w = (mat == 0) ? w0 : (mat == 1) ? w1 : (mat == 2) ? w2 : w3;
    wt[((size_t)(mat * 256 + c)) * 256 + k] = f2bf(w[k * 256 + c]);
}

// ---------------- adjacency -> bitmask (streaming) ----------------
// Phase-split for MLP: 16 independent int4 loads into v[16], then pack.
__global__ __launch_bounds__(256) void k_mask(const int* __restrict__ adj,
                                              unsigned int* __restrict__ mbg) {
    int wave = (blockIdx.x * 256 + threadIdx.x) >> 6;   // 0..8191
    int lane = threadIdx.x & 63;
    int shamt = 4 * (lane & 7);
    int g8 = lane >> 3;
    const int4* p = reinterpret_cast<const int4*>(adj) + (size_t)wave * 1024 + lane;
    unsigned int* outp = mbg + (size_t)wave * 128;

    int4 v[16];
#pragma unroll
    for (int i = 0; i < 16; ++i)
        v[i] = p[i * 64];

#pragma unroll
    for (int i = 0; i < 16; ++i) {
        unsigned int nib = (v[i].x != 0 ? 1u : 0u) | (v[i].y != 0 ? 2u : 0u)
                         | (v[i].z != 0 ? 4u : 0u) | (v[i].w != 0 ? 8u : 0u);
        unsigned int r = nib << shamt;
        r |= (unsigned int)__shfl_xor((int)r, 1, 64);
        r |= (unsigned int)__shfl_xor((int)r, 2, 64);
        r |= (unsigned int)__shfl_xor((int)r, 4, 64);
        if ((lane & 7) == 0) outp[i * 8 + g8] = r;
    }
}

// ---------------- fused QKV projection GEMM ----------------
// Q row-major [bh][n][hd] (scaled). K,V in MFMA fragment-tile order (per bh,
// tile t = 1024 ush; frag f = 512 ush; slot lane*8): direct 1KB wave loads.
__global__ __launch_bounds__(256) void k_qkv(const unsigned short* __restrict__ xbf,
                                             const unsigned short* __restrict__ wt,
                                             const float* __restrict__ bq, const float* __restrict__ bk,
                                             const float* __restrict__ bv,
                                             unsigned short* __restrict__ Qb, unsigned short* __restrict__ Ks,
                                             unsigned short* __restrict__ Vs) {
    int mat = blockIdx.y;
    int lane = threadIdx.x & 63;
    int wv = threadIdx.x >> 6;
    int row0 = blockIdx.x * 64 + wv * 16;
    int l15 = lane & 15, lg = lane >> 4;
    const float* bias = (mat == 0) ? bq : (mat == 1) ? bk : bv;
    const float qs = (mat == 0) ? QSCALE : 1.0f;
    const unsigned short* wm = wt + (size_t)mat * 65536;

    short8 af[8];
    const unsigned short* xrow = xbf + (size_t)(row0 + l15) * 256 + lg * 8;
#pragma unroll
    for (int kk = 0; kk < 8; ++kk)
        af[kk] = *reinterpret_cast<const short8*>(xrow + kk * 32);

    int b = row0 >> 11;            // 2048 rows per batch; 64-row blocks never cross
    int nbase = (row0 & 2047) + lg * 4;

    for (int ci = 0; ci < 16; ++ci) {
        const unsigned short* wrow = wm + (size_t)(ci * 16 + l15) * 256 + lg * 8;
        f32x4 acc = {0.f, 0.f, 0.f, 0.f};
#pragma unroll
        for (int kk = 0; kk < 8; ++kk) {
            short8 bfg = *reinterpret_cast<const short8*>(wrow + kk * 32);
            acc = __builtin_amdgcn_mfma_f32_16x16x32_bf16(af[kk], bfg, acc, 0, 0, 0);
        }
        int col = ci * 16 + l15;
        float bcol = bias[col];
        int h = col >> 5, hd = col & 31;
        size_t bh64 = (size_t)(b * 8 + h) * 65536;
        if (mat == 0) {
#pragma unroll
            for (int r = 0; r < 4; ++r)
                Qb[bh64 + (size_t)(nbase + r) * 32 + hd] = f2bf((acc[r] + bcol) * qs);
        } else if (mat == 1) {
#pragma unroll
            for (int r = 0; r < 4; ++r) {
                int n = nbase + r;
                size_t off = bh64 + (size_t)(n >> 5) * 1024 + (hd >> 4) * 512
                           + (((hd >> 3) & 1) * 32 + (n & 31)) * 8 + (hd & 7);
                Ks[off] = f2bf(acc[r] + bcol);
            }
        } else {
            int posb = nbase & 31;
            size_t off = bh64 + (size_t)(nbase >> 5) * 1024 + (posb >> 4) * 512
                       + ((((posb >> 3) & 1) * 32 + hd)) * 8 + (posb & 7);
            ushort4 o;
            o.x = f2bf(acc[0] + bcol); o.y = f2bf(acc[1] + bcol);
            o.z = f2bf(acc[2] + bcol); o.w = f2bf(acc[3] + bcol);
            *reinterpret_cast<ushort4*>(Vs + off) = o;
        }
    }
}

// ---------------- masked attention ----------------
// Direct-from-L2 (no K/V LDS staging). blk: b = blk&7 (XCD), hg = (blk>>3)&1,
// q0 = (blk>>4)*32; 4 waves = 4 heads. 8KB bitmask preloaded to LDS once.
// Masking via 16-entry LDS LUT: nibble -> uint2 pair-mask (conflict-free:
// entry i occupies banks {2i,2i+1}; distinct nibbles hit distinct banks),
// ANDed onto packed-bf16 cvtpk output: 1 bfe + 1 ds_read_b64 + 2 v_and per
// group vs 12 cmp/cndmask VALU ops. S^T = mfma(K,Q); permlane32_swap -> PV
// B-frag; att^T += mfma(V,P); denominator via ones-MFMA.
__global__ __launch_bounds__(256, 6) void k_attn(const unsigned short* __restrict__ Qb,
                                                 const unsigned short* __restrict__ Ks,
                                                 const unsigned short* __restrict__ Vs,
                                                 const unsigned int* __restrict__ mbg,
                                                 unsigned short* __restrict__ att) {
    __shared__ unsigned int mbits[32][66];   // +2 pad: 2-way max conflict (free)
    __shared__ uint2 lut16[16];
    int tid = threadIdx.x;
    int lane = tid & 63, wv = tid >> 6;
    int l31 = lane & 31, hi = lane >> 5;
    int b = blockIdx.x & 7;
    int hg = (blockIdx.x >> 3) & 1;
    int q0 = (blockIdx.x >> 4) * 32;
    int head = hg * 4 + wv;
    int bh = b * 8 + head;

    // ---- preload 8KB bitmask + build pair-mask LUT ----
    {
        int row = tid >> 3, c0 = (tid & 7) * 8;
        const unsigned int* src = mbg + ((size_t)(b * N_ + q0 + row)) * 64 + c0;
        uint4 v4 = *reinterpret_cast<const uint4*>(src);
        uint4 w4 = *reinterpret_cast<const uint4*>(src + 4);
        mbits[row][c0 + 0] = v4.x; mbits[row][c0 + 1] = v4.y;
        mbits[row][c0 + 2] = v4.z; mbits[row][c0 + 3] = v4.w;
        mbits[row][c0 + 4] = w4.x; mbits[row][c0 + 5] = w4.y;
        mbits[row][c0 + 6] = w4.z; mbits[row][c0 + 7] = w4.w;
        if (tid < 16) {
            uint2 e;
            e.x = (tid & 1 ? 0xFFFFu : 0u) | (tid & 2 ? 0xFFFF0000u : 0u);
            e.y = (tid & 4 ? 0xFFFFu : 0u) | (tid & 8 ? 0xFFFF0000u : 0u);
            lut16[tid] = e;
        }
    }
    __syncthreads();

    const unsigned short* gK = Ks + (size_t)bh * 65536 + (size_t)lane * 8;
    const unsigned short* gV = Vs + (size_t)bh * 65536 + (size_t)lane * 8;
    const unsigned short* Qh = Qb + (size_t)bh * 65536;
    const unsigned int* mrow = &mbits[l31][0];

    short8 qf0 = *reinterpret_cast<const short8*>(Qh + (size_t)(q0 + l31) * 32 + hi * 8);
    short8 qf1 = *reinterpret_cast<const short8*>(Qh + (size_t)(q0 + l31) * 32 + hi * 8 + 16);

    const f32x16 fz = {0.f,0.f,0.f,0.f,0.f,0.f,0.f,0.f,0.f,0.f,0.f,0.f,0.f,0.f,0.f,0.f};
    const short8 onesf = {0x3F80, 0x3F80, 0x3F80, 0x3F80, 0x3F80, 0x3F80, 0x3F80, 0x3F80};
    f32x16 attacc = fz;
    f32x16 onesacc = fz;

#pragma unroll 2
    for (int t = 0; t < 64; ++t) {
        short8 kf0 = *reinterpret_cast<const short8*>(gK + (size_t)t * 1024);
        short8 kf1 = *reinterpret_cast<const short8*>(gK + (size_t)t * 1024 + 512);
        short8 vf0 = *reinterpret_cast<const short8*>(gV + (size_t)t * 1024);
        short8 vf1 = *reinterpret_cast<const short8*>(gV + (size_t)t * 1024 + 512);
        unsigned int wl = mrow[t] >> (4 * hi);

        __builtin_amdgcn_s_setprio(1);
        f32x16 s = __builtin_amdgcn_mfma_f32_32x32x16_bf16(kf0, qf0, fz, 0, 0, 0);
        s = __builtin_amdgcn_mfma_f32_32x32x16_bf16(kf1, qf1, s, 0, 0, 0);
        __builtin_amdgcn_s_setprio(0);

        uint2 m0 = lut16[wl & 15u];
        uint2 m1 = lut16[(wl >> 8) & 15u];
        uint2 m2 = lut16[(wl >> 16) & 15u];
        uint2 m3 = lut16[(wl >> 24) & 15u];

        unsigned int pd[4][2];
        pd[0][0] = cvtpk(exp2v(s[0]),  exp2v(s[1]))  & m0.x;
        pd[0][1] = cvtpk(exp2v(s[2]),  exp2v(s[3]))  & m0.y;
        pd[1][0] = cvtpk(exp2v(s[4]),  exp2v(s[5]))  & m1.x;
        pd[1][1] = cvtpk(exp2v(s[6]),  exp2v(s[7]))  & m1.y;
        pd[2][0] = cvtpk(exp2v(s[8]),  exp2v(s[9]))  & m2.x;
        pd[2][1] = cvtpk(exp2v(s[10]), exp2v(s[11])) & m2.y;
        pd[3][0] = cvtpk(exp2v(s[12]), exp2v(s[13])) & m3.x;
        pd[3][1] = cvtpk(exp2v(s[14]), exp2v(s[15])) & m3.y;

        asm("v_permlane32_swap_b32 %0, %1" : "+v"(pd[0][0]), "+v"(pd[1][0]));
        asm("v_permlane32_swap_b32 %0, %1" : "+v"(pd[0][1]), "+v"(pd[1][1]));
        asm("v_permlane32_swap_b32 %0, %1" : "+v"(pd[2][0]), "+v"(pd[3][0]));
        asm("v_permlane32_swap_b32 %0, %1" : "+v"(pd[2][1]), "+v"(pd[3][1]));

        union { short8 s8; unsigned int u[4]; } bf0, bf1;
        bf0.u[0] = pd[0][0]; bf0.u[1] = pd[0][1]; bf0.u[2] = pd[1][0]; bf0.u[3] = pd[1][1];
        bf1.u[0] = pd[2][0]; bf1.u[1] = pd[2][1]; bf1.u[2] = pd[3][0]; bf1.u[3] = pd[3][1];

        __builtin_amdgcn_s_setprio(1);
        attacc = __builtin_amdgcn_mfma_f32_32x32x16_bf16(vf0, bf0.s8, attacc, 0, 0, 0);
        attacc = __builtin_amdgcn_mfma_f32_32x32x16_bf16(vf1, bf1.s8, attacc, 0, 0, 0);
        onesacc = __builtin_amdgcn_mfma_f32_32x32x16_bf16(onesf, bf0.s8, onesacc, 0, 0, 0);
        onesacc = __builtin_amdgcn_mfma_f32_32x32x16_bf16(onesf, bf1.s8, onesacc, 0, 0, 0);
        __builtin_amdgcn_s_setprio(0);
    }

    float rcp = 1.f / onesacc[0];   // every reg holds sum_k P[k][q=l31]

    unsigned short* arow = att + ((size_t)b * N_ + q0 + l31) * D_ + head * HD_;
#pragma unroll
    for (int g = 0; g < 4; ++g) {
        ushort4 o;
        o.x = f2bf(attacc[4 * g + 0] * rcp);
        o.y = f2bf(attacc[4 * g + 1] * rcp);
        o.z = f2bf(attacc[4 * g + 2] * rcp);
        o.w = f2bf(attacc[4 * g + 3] * rcp);
        *reinterpret_cast<ushort4*>(arow + 8 * g + 4 * hi) = o;
    }
}

// ---------------- out projection + residual + LayerNorm ----------------
__global__ __launch_bounds__(256) void k_outln(const unsigned short* __restrict__ att,
                                               const unsigned short* __restrict__ wot,
                                               const float* __restrict__ bo,
                                               const unsigned short* __restrict__ xbf,
                                               const float* __restrict__ gamma, const float* __restrict__ beta,
                                               float* __restrict__ out) {
    int lane = threadIdx.x & 63, wv = threadIdx.x >> 6;
    int l15 = lane & 15, lg = lane >> 4;
    int row0 = blockIdx.x * 64 + wv * 16;

    short8 af[8];
    const unsigned short* arow = att + (size_t)(row0 + l15) * 256 + lg * 8;
#pragma unroll
    for (int kk = 0; kk < 8; ++kk)
        af[kk] = *reinterpret_cast<const short8*>(arow + kk * 32);

    float v[16][4];
#pragma unroll
    for (int ci = 0; ci < 16; ++ci) {
        const unsigned short* wrow = wot + (size_t)(ci * 16 + l15) * 256 + lg * 8;
        f32x4 acc = {0.f, 0.f, 0.f, 0.f};
#pragma unroll
        for (int kk = 0; kk < 8; ++kk) {
            short8 bfg = *reinterpret_cast<const short8*>(wrow + kk * 32);
            acc = __builtin_amdgcn_mfma_f32_16x16x32_bf16(af[kk], bfg, acc, 0, 0, 0);
        }
        float bcol = bo[ci * 16 + l15];
#pragma unroll
        for (int r = 0; r < 4; ++r)
            v[ci][r] = acc[r] + bcol + bf2f(xbf[(size_t)(row0 + lg * 4 + r) * 256 + ci * 16 + l15]);
    }

    float sum[4] = {0.f, 0.f, 0.f, 0.f}, sq[4] = {0.f, 0.f, 0.f, 0.f};
#pragma unroll
    for (int ci = 0; ci < 16; ++ci)
#pragma unroll
        for (int r = 0; r < 4; ++r) {
            sum[r] += v[ci][r];
            sq[r] += v[ci][r] * v[ci][r];
        }
#pragma unroll
    for (int d = 1; d < 16; d <<= 1)
#pragma unroll
        for (int r = 0; r < 4; ++r) {
            sum[r] += __shfl_xor(sum[r], d, 64);
            sq[r] += __shfl_xor(sq[r], d, 64);
        }

    float mu[4], rs[4];
#pragma unroll
    for (int r = 0; r < 4; ++r) {
        mu[r] = sum[r] * (1.f / 256.f);
        float var = sq[r] * (1.f / 256.f) - mu[r] * mu[r];
        rs[r] = rsqrtf(var + LN_EPS);
    }

#pragma unroll
    for (int ci = 0; ci < 16; ++ci) {
        float g = gamma[ci * 16 + l15], be = beta[ci * 16 + l15];
#pragma unroll
        for (int r = 0; r < 4; ++r)
            out[(size_t)(row0 + lg * 4 + r) * 256 + ci * 16 + l15] = (v[ci][r] - mu[r]) * rs[r] * g + be;
    }
}

extern "C" void kernel_launch(void* const* d_in, const int* in_sizes, int n_in,
                              void* d_out, int out_size, void* d_ws, size_t ws_size,
                              hipStream_t stream) {
    (void)in_sizes; (void)n_in; (void)out_size; (void)ws_size;
    const float* x     = (const float*)d_in[0];
    const int*   adj   = (const int*)d_in[1];
    const float* Wq    = (const float*)d_in[2];
    const float* bq    = (const float*)d_in[3];
    const float* Wk    = (const float*)d_in[4];
    const float* bk    = (const float*)d_in[5];
    const float* Wv    = (const float*)d_in[6];
    const float* bv    = (const float*)d_in[7];
    const float* Wo    = (const float*)d_in[8];
    const float* bo    = (const float*)d_in[9];
    const float* gamma = (const float*)d_in[10];
    const float* beta  = (const float*)d_in[11];
    float* out = (float*)d_out;

    char* ws = (char*)d_ws;
    unsigned short* xbf = (unsigned short*)ws; ws += (size_t)16384 * 256 * 2;   // 8.4 MB
    unsigned short* wt  = (unsigned short*)ws; ws += (size_t)4 * 256 * 256 * 2; // 0.5 MB (q,k,v,o)
    unsigned short* Qb  = (unsigned short*)ws; ws += (size_t)B_ * H_ * N_ * HD_ * 2; // 8.4 MB
    unsigned short* Ks  = (unsigned short*)ws; ws += (size_t)B_ * H_ * N_ * HD_ * 2;
    unsigned short* Vs  = (unsigned short*)ws; ws += (size_t)B_ * H_ * N_ * HD_ * 2;
    unsigned short* att = (unsigned short*)ws; ws += (size_t)16384 * 256 * 2;
    unsigned int*   mbg = (unsigned int*)ws;   ws += (size_t)B_ * N_ * 64 * 4;  // 4.2 MB

    k_prep_x<<<4096, 256, 0, stream>>>(x, xbf, 1048576);
    k_prep_w<<<dim3(256, 4), 256, 0, stream>>>(Wq, Wk, Wv, Wo, wt);
    k_mask<<<2048, 256, 0, stream>>>(adj, mbg);
    k_qkv<<<dim3(256, 3), 256, 0, stream>>>(xbf, wt, bq, bk, bv, Qb, Ks, Vs);
    k_attn<<<1024, 256, 0, stream>>>(Qb, Ks, Vs, mbg, att);
    k_outln<<<256, 256, 0, stream>>>(att, wt + 3 * 65536, bo, xbf, gamma, beta, out);
}

// Round 11
// 183.790 us; speedup vs baseline: 1.2151x; 1.0499x over previous
//
#include <hip/hip_runtime.h>
#include <hip/hip_bf16.h>
#include <cstdint>
#include <cstddef>

// Problem constants
#define B_ 8
#define N_ 2048
#define D_ 256
#define H_ 8
#define HD_ 32
#define LN_EPS 1e-5f
#define QSCALE 0.25506275f  // log2(e)/sqrt(32): folded into Q so p = exp2(q'.k)

typedef __attribute__((ext_vector_type(8))) short short8;
typedef __attribute__((ext_vector_type(4))) float f32x4;
typedef __attribute__((ext_vector_type(16))) float f32x16;

static __device__ __forceinline__ float exp2v(float x) {
#if __has_builtin(__builtin_amdgcn_exp2f)
    return __builtin_amdgcn_exp2f(x);
#else
    float r;
    asm("v_exp_f32 %0, %1" : "=v"(r) : "v"(x));
    return r;
#endif
}

static __device__ __forceinline__ unsigned short f2bf(float f) {
    union { float f; unsigned int u; } v; v.f = f;
    unsigned int r = v.u + 0x7fffu + ((v.u >> 16) & 1u);
    return (unsigned short)(r >> 16);
}

static __device__ __forceinline__ unsigned int cvtpk(float lo, float hi) {
    unsigned int d;
    asm("v_cvt_pk_bf16_f32 %0, %1, %2" : "=v"(d) : "v"(lo), "v"(hi));
    return d;
}

// ---------------- prep: W fp32 -> bf16 transposed wt[mat][col][k] ----------------
__global__ __launch_bounds__(256) void k_prep_w(const float* __restrict__ w0, const float* __restrict__ w1,
                                                const float* __restrict__ w2, const float* __restrict__ w3,
                                                unsigned short* __restrict__ wt) {
    int c = blockIdx.x, mat = blockIdx.y, k = threadIdx.x;
    const float* w = (mat == 0) ? w0 : (mat == 1) ? w1 : (mat == 2) ? w2 : w3;
    wt[((size_t)(mat * 256 + c)) * 256 + k] = f2bf(w[k * 256 + c]);
}

// ---------------- adjacency -> bitmask (streaming, forced MLP) ----------------
// 16384 waves x 8KB. Phase 1: 8 independent int4 loads; sched_barrier(0) pins
// them BEFORE the pack phase (compiler cannot sink loads into the consumer
// loop, which previously serialized to 1 outstanding load -> 80us).
// Phase 2: nibble build + 3x shfl-OR + masked store per iter.
__global__ __launch_bounds__(256) void k_mask(const int* __restrict__ adj,
                                              unsigned int* __restrict__ mbg) {
    int wave = (blockIdx.x * 256 + threadIdx.x) >> 6;   // 0..16383
    int lane = threadIdx.x & 63;
    int shamt = 4 * (lane & 7);
    int g8 = lane >> 3;
    const int4* p = reinterpret_cast<const int4*>(adj) + (size_t)wave * 512 + lane;
    unsigned int* outp = mbg + (size_t)wave * 64;

    int4 v[8];
#pragma unroll
    for (int i = 0; i < 8; ++i)
        v[i] = p[i * 64];
    __builtin_amdgcn_sched_barrier(0);

#pragma unroll
    for (int i = 0; i < 8; ++i) {
        unsigned int nib = (v[i].x != 0 ? 1u : 0u) | (v[i].y != 0 ? 2u : 0u)
                         | (v[i].z != 0 ? 4u : 0u) | (v[i].w != 0 ? 8u : 0u);
        unsigned int r = nib << shamt;
        r |= (unsigned int)__shfl_xor((int)r, 1, 64);
        r |= (unsigned int)__shfl_xor((int)r, 2, 64);
        r |= (unsigned int)__shfl_xor((int)r, 4, 64);
        if ((lane & 7) == 0) outp[i * 8 + g8] = r;
    }
}

// ---------------- fused QKV projection GEMM (reads fp32 x directly) ----------------
// A-fragments built in-reg via v_cvt_pk_bf16_f32 (RTNE, matches f2bf exactly).
// Q row-major [bh][n][hd] (scaled); K row-major; V fragment-tile order.
__global__ __launch_bounds__(256) void k_qkv(const float* __restrict__ x,
                                             const unsigned short* __restrict__ wt,
                                             const float* __restrict__ bq, const float* __restrict__ bk,
                                             const float* __restrict__ bv,
                                             unsigned short* __restrict__ Qb, unsigned short* __restrict__ Kb,
                                             unsigned short* __restrict__ Vs) {
    int mat = blockIdx.y;
    int lane = threadIdx.x & 63;
    int wv = threadIdx.x >> 6;
    int row0 = blockIdx.x * 64 + wv * 16;
    int l15 = lane & 15, lg = lane >> 4;
    const float* bias = (mat == 0) ? bq : (mat == 1) ? bk : bv;
    const float qs = (mat == 0) ? QSCALE : 1.0f;
    const unsigned short* wm = wt + (size_t)mat * 65536;

    short8 af[8];
    const float* xrow = x + (size_t)(row0 + l15) * 256 + lg * 8;
#pragma unroll
    for (int kk = 0; kk < 8; ++kk) {
        float4 a = *reinterpret_cast<const float4*>(xrow + kk * 32);
        float4 b = *reinterpret_cast<const float4*>(xrow + kk * 32 + 4);
        union { short8 s8; unsigned int u[4]; } t;
        t.u[0] = cvtpk(a.x, a.y); t.u[1] = cvtpk(a.z, a.w);
        t.u[2] = cvtpk(b.x, b.y); t.u[3] = cvtpk(b.z, b.w);
        af[kk] = t.s8;
    }

    int b = row0 >> 11;            // 2048 rows per batch; 64-row blocks never cross
    int nbase = (row0 & 2047) + lg * 4;

    for (int ci = 0; ci < 16; ++ci) {
        const unsigned short* wrow = wm + (size_t)(ci * 16 + l15) * 256 + lg * 8;
        f32x4 acc = {0.f, 0.f, 0.f, 0.f};
#pragma unroll
        for (int kk = 0; kk < 8; ++kk) {
            short8 bfg = *reinterpret_cast<const short8*>(wrow + kk * 32);
            acc = __builtin_amdgcn_mfma_f32_16x16x32_bf16(af[kk], bfg, acc, 0, 0, 0);
        }
        int col = ci * 16 + l15;
        float bcol = bias[col];
        int h = col >> 5, hd = col & 31;
        if (mat < 2) {
            unsigned short* dst = (mat == 0) ? Qb : Kb;
#pragma unroll
            for (int r = 0; r < 4; ++r) {
                size_t off = ((size_t)(b * 8 + h) * 2048 + nbase + r) * 32 + hd;
                dst[off] = f2bf((acc[r] + bcol) * qs);
            }
        } else {
            // V fragment-tile layout
            size_t off = (size_t)(b * 8 + h) * 65536
                       + ((size_t)(nbase >> 4) * 32 + hd) * 16 + (nbase & 15);
            ushort4 o;
            o.x = f2bf(acc[0] + bcol); o.y = f2bf(acc[1] + bcol);
            o.z = f2bf(acc[2] + bcol); o.w = f2bf(acc[3] + bcol);
            *reinterpret_cast<ushort4*>(Vs + off) = o;
        }
    }
}

// ---------------- masked attention (R7 structure, proven 77.5us) ----------------
// 256-thr blocks (4 waves = 4 heads), blk: b = blk&7 (XCD), hg = (blk>>3)&1,
// q0 = (blk>>4)*32. 8KB bitmask preloaded to LDS. Direct-from-L2 K/V loads.
// S^T = mfma(K,Q); p = bit ? exp2(s) : 0; cvt_pk + permlane32_swap -> PV
// B-frag; att^T += mfma(V,P); denominator via ones-MFMA.
__global__ __launch_bounds__(256, 6) void k_attn(const unsigned short* __restrict__ Qb,
                                                 const unsigned short* __restrict__ Kb,
                                                 const unsigned short* __restrict__ Vs,
                                                 const unsigned int* __restrict__ mbg,
                                                 unsigned short* __restrict__ att) {
    __shared__ unsigned int mbits[32][66];   // +2 pad: 2-way max conflict (free)
    int tid = threadIdx.x;
    int lane = tid & 63;
    int l31 = lane & 31, hi = lane >> 5;
    int b = blockIdx.x & 7;
    int hg = (blockIdx.x >> 3) & 1;
    int q0 = (blockIdx.x >> 4) * 32;
    int head = hg * 4 + (tid >> 6);

    // ---- load this block's 8KB bitmask (two uint4 per thread) ----
    {
        int row = tid >> 3, c0 = (tid & 7) * 8;
        const unsigned int* src = mbg + ((size_t)(b * N_ + q0 + row)) * 64 + c0;
        uint4 v4 = *reinterpret_cast<const uint4*>(src);
        uint4 w4 = *reinterpret_cast<const uint4*>(src + 4);
        mbits[row][c0 + 0] = v4.x; mbits[row][c0 + 1] = v4.y;
        mbits[row][c0 + 2] = v4.z; mbits[row][c0 + 3] = v4.w;
        mbits[row][c0 + 4] = w4.x; mbits[row][c0 + 5] = w4.y;
        mbits[row][c0 + 6] = w4.z; mbits[row][c0 + 7] = w4.w;
    }
    __syncthreads();

    int bh = b * 8 + head;
    const unsigned short* Qh = Qb + (size_t)bh * N_ * HD_;
    const unsigned short* Kh = Kb + (size_t)bh * N_ * HD_;
    const unsigned short* Vh = Vs + (size_t)bh * 65536;

    short8 qf0 = *reinterpret_cast<const short8*>(Qh + (size_t)(q0 + l31) * HD_ + hi * 8);
    short8 qf1 = *reinterpret_cast<const short8*>(Qh + (size_t)(q0 + l31) * HD_ + hi * 8 + 16);
    const unsigned short* krow = Kh + (size_t)l31 * HD_ + hi * 8;
    const unsigned short* vfp = Vh + (size_t)l31 * 16 + hi * 8;   // + tile*512

    const f32x16 fz = {0.f,0.f,0.f,0.f,0.f,0.f,0.f,0.f,0.f,0.f,0.f,0.f,0.f,0.f,0.f,0.f};
    const short8 onesf = {0x3F80, 0x3F80, 0x3F80, 0x3F80, 0x3F80, 0x3F80, 0x3F80, 0x3F80};
    f32x16 attacc = fz;
    f32x16 onesacc = fz;
    const unsigned int* mrow = &mbits[l31][0];

#pragma unroll 2
    for (int m0 = 0; m0 < N_; m0 += 32) {
        short8 kf0 = *reinterpret_cast<const short8*>(krow + (size_t)m0 * HD_);
        short8 kf1 = *reinterpret_cast<const short8*>(krow + (size_t)m0 * HD_ + 16);
        short8 vf0 = *reinterpret_cast<const short8*>(vfp + (size_t)(m0 >> 4) * 512);
        short8 vf1 = *reinterpret_cast<const short8*>(vfp + (size_t)(m0 >> 4) * 512 + 512);
        unsigned int wl = mrow[m0 >> 5] >> (4 * hi);   // lane's bits now at 8g..8g+3

        __builtin_amdgcn_s_setprio(1);
        f32x16 s = __builtin_amdgcn_mfma_f32_32x32x16_bf16(kf0, qf0, fz, 0, 0, 0);
        s = __builtin_amdgcn_mfma_f32_32x32x16_bf16(kf1, qf1, s, 0, 0, 0);
        __builtin_amdgcn_s_setprio(0);

        unsigned int pd[4][2];
#pragma unroll
        for (int g = 0; g < 4; ++g) {
            unsigned int nib = (wl >> (8 * g)) & 15u;
            float p0 = (nib & 1u) ? exp2v(s[4 * g + 0]) : 0.f;
            float p1 = (nib & 2u) ? exp2v(s[4 * g + 1]) : 0.f;
            float p2 = (nib & 4u) ? exp2v(s[4 * g + 2]) : 0.f;
            float p3 = (nib & 8u) ? exp2v(s[4 * g + 3]) : 0.f;
            pd[g][0] = cvtpk(p0, p1);
            pd[g][1] = cvtpk(p2, p3);
        }
        asm("v_permlane32_swap_b32 %0, %1" : "+v"(pd[0][0]), "+v"(pd[1][0]));
        asm("v_permlane32_swap_b32 %0, %1" : "+v"(pd[0][1]), "+v"(pd[1][1]));
        asm("v_permlane32_swap_b32 %0, %1" : "+v"(pd[2][0]), "+v"(pd[3][0]));
        asm("v_permlane32_swap_b32 %0, %1" : "+v"(pd[2][1]), "+v"(pd[3][1]));

        union { short8 s8; unsigned int u[4]; } bf0, bf1;
        bf0.u[0] = pd[0][0]; bf0.u[1] = pd[0][1]; bf0.u[2] = pd[1][0]; bf0.u[3] = pd[1][1];
        bf1.u[0] = pd[2][0]; bf1.u[1] = pd[2][1]; bf1.u[2] = pd[3][0]; bf1.u[3] = pd[3][1];

        __builtin_amdgcn_s_setprio(1);
        attacc = __builtin_amdgcn_mfma_f32_32x32x16_bf16(vf0, bf0.s8, attacc, 0, 0, 0);
        attacc = __builtin_amdgcn_mfma_f32_32x32x16_bf16(vf1, bf1.s8, attacc, 0, 0, 0);
        onesacc = __builtin_amdgcn_mfma_f32_32x32x16_bf16(onesf, bf0.s8, onesacc, 0, 0, 0);
        onesacc = __builtin_amdgcn_mfma_f32_32x32x16_bf16(onesf, bf1.s8, onesacc, 0, 0, 0);
        __builtin_amdgcn_s_setprio(0);
    }

    float rcp = 1.f / onesacc[0];   // every reg holds sum_k P[k][q=l31]

    unsigned short* arow = att + ((size_t)b * N_ + q0 + l31) * D_ + head * HD_;
#pragma unroll
    for (int g = 0; g < 4; ++g) {
        ushort4 o;
        o.x = f2bf(attacc[4 * g + 0] * rcp);
        o.y = f2bf(attacc[4 * g + 1] * rcp);
        o.z = f2bf(attacc[4 * g + 2] * rcp);
        o.w = f2bf(attacc[4 * g + 3] * rcp);
        *reinterpret_cast<ushort4*>(arow + 8 * g + 4 * hi) = o;
    }
}

// ---------------- out projection + residual + LayerNorm ----------------
// Residual from fp32 x (exact, removes xbf dependency).
__global__ __launch_bounds__(256) void k_outln(const unsigned short* __restrict__ att,
                                               const unsigned short* __restrict__ wot,
                                               const float* __restrict__ bo,
                                               const float* __restrict__ x,
                                               const float* __restrict__ gamma, const float* __restrict__ beta,
                                               float* __restrict__ out) {
    int lane = threadIdx.x & 63, wv = threadIdx.x >> 6;
    int l15 = lane & 15, lg = lane >> 4;
    int row0 = blockIdx.x * 64 + wv * 16;

    short8 af[8];
    const unsigned short* arow = att + (size_t)(row0 + l15) * 256 + lg * 8;
#pragma unroll
    for (int kk = 0; kk < 8; ++kk)
        af[kk] = *reinterpret_cast<const short8*>(arow + kk * 32);

    float v[16][4];
#pragma unroll
    for (int ci = 0; ci < 16; ++ci) {
        const unsigned short* wrow = wot + (size_t)(ci * 16 + l15) * 256 + lg * 8;
        f32x4 acc = {0.f, 0.f, 0.f, 0.f};
#pragma unroll
        for (int kk = 0; kk < 8; ++kk) {
            short8 bfg = *reinterpret_cast<const short8*>(wrow + kk * 32);
            acc = __builtin_amdgcn_mfma_f32_16x16x32_bf16(af[kk], bfg, acc, 0, 0, 0);
        }
        float bcol = bo[ci * 16 + l15];
#pragma unroll
        for (int r = 0; r < 4; ++r)
            v[ci][r] = acc[r] + bcol + x[(size_t)(row0 + lg * 4 + r) * 256 + ci * 16 + l15];
    }

    float sum[4] = {0.f, 0.f, 0.f, 0.f}, sq[4] = {0.f, 0.f, 0.f, 0.f};
#pragma unroll
    for (int ci = 0; ci < 16; ++ci)
#pragma unroll
        for (int r = 0; r < 4; ++r) {
            sum[r] += v[ci][r];
            sq[r] += v[ci][r] * v[ci][r];
        }
#pragma unroll
    for (int d = 1; d < 16; d <<= 1)
#pragma unroll
        for (int r = 0; r < 4; ++r) {
            sum[r] += __shfl_xor(sum[r], d, 64);
            sq[r] += __shfl_xor(sq[r], d, 64);
        }

    float mu[4], rs[4];
#pragma unroll
    for (int r = 0; r < 4; ++r) {
        mu[r] = sum[r] * (1.f / 256.f);
        float var = sq[r] * (1.f / 256.f) - mu[r] * mu[r];
        rs[r] = rsqrtf(var + LN_EPS);
    }

#pragma unroll
    for (int ci = 0; ci < 16; ++ci) {
        float g = gamma[ci * 16 + l15], be = beta[ci * 16 + l15];
#pragma unroll
        for (int r = 0; r < 4; ++r)
            out[(size_t)(row0 + lg * 4 + r) * 256 + ci * 16 + l15] = (v[ci][r] - mu[r]) * rs[r] * g + be;
    }
}

extern "C" void kernel_launch(void* const* d_in, const int* in_sizes, int n_in,
                              void* d_out, int out_size, void* d_ws, size_t ws_size,
                              hipStream_t stream) {
    (void)in_sizes; (void)n_in; (void)out_size; (void)ws_size;
    const float* x     = (const float*)d_in[0];
    const int*   adj   = (const int*)d_in[1];
    const float* Wq    = (const float*)d_in[2];
    const float* bq    = (const float*)d_in[3];
    const float* Wk    = (const float*)d_in[4];
    const float* bk    = (const float*)d_in[5];
    const float* Wv    = (const float*)d_in[6];
    const float* bv    = (const float*)d_in[7];
    const float* Wo    = (const float*)d_in[8];
    const float* bo    = (const float*)d_in[9];
    const float* gamma = (const float*)d_in[10];
    const float* beta  = (const float*)d_in[11];
    float* out = (float*)d_out;

    char* ws = (char*)d_ws;
    unsigned short* wt  = (unsigned short*)ws; ws += (size_t)4 * 256 * 256 * 2; // 0.5 MB (q,k,v,o)
    unsigned short* Qb  = (unsigned short*)ws; ws += (size_t)B_ * H_ * N_ * HD_ * 2; // 8.4 MB
    unsigned short* Kb  = (unsigned short*)ws; ws += (size_t)B_ * H_ * N_ * HD_ * 2;
    unsigned short* Vs  = (unsigned short*)ws; ws += (size_t)B_ * H_ * N_ * HD_ * 2;
    unsigned short* att = (unsigned short*)ws; ws += (size_t)16384 * 256 * 2;
    unsigned int*   mbg = (unsigned int*)ws;   ws += (size_t)B_ * N_ * 64 * 4;  // 4.2 MB

    k_prep_w<<<dim3(256, 4), 256, 0, stream>>>(Wq, Wk, Wv, Wo, wt);
    k_mask<<<4096, 256, 0, stream>>>(adj, mbg);
    k_qkv<<<dim3(256, 3), 256, 0, stream>>>(x, wt, bq, bk, bv, Qb, Kb, Vs);
    k_attn<<<1024, 256, 0, stream>>>(Qb, Kb, Vs, mbg, att);
    k_outln<<<256, 256, 0, stream>>>(att, wt + 3 * 65536, bo, x, gamma, beta, out);
}

// Round 12
// 183.302 us; speedup vs baseline: 1.2183x; 1.0027x over previous
//
#include <hip/hip_runtime.h>
#include <hip/hip_bf16.h>
#include <cstdint>
#include <cstddef>

// Problem constants
#define B_ 8
#define N_ 2048
#define D_ 256
#define H_ 8
#define HD_ 32
#define LN_EPS 1e-5f
#define QSCALE 0.25506275f  // log2(e)/sqrt(32): folded into Q so p = exp2(q'.k)

typedef __attribute__((ext_vector_type(8))) short short8;
typedef __attribute__((ext_vector_type(4))) float f32x4;
typedef __attribute__((ext_vector_type(16))) float f32x16;

static __device__ __forceinline__ float exp2v(float x) {
#if __has_builtin(__builtin_amdgcn_exp2f)
    return __builtin_amdgcn_exp2f(x);
#else
    float r;
    asm("v_exp_f32 %0, %1" : "=v"(r) : "v"(x));
    return r;
#endif
}

static __device__ __forceinline__ unsigned short f2bf(float f) {
    union { float f; unsigned int u; } v; v.f = f;
    unsigned int r = v.u + 0x7fffu + ((v.u >> 16) & 1u);
    return (unsigned short)(r >> 16);
}

static __device__ __forceinline__ unsigned int cvtpk(float lo, float hi) {
    unsigned int d;
    asm("v_cvt_pk_bf16_f32 %0, %1, %2" : "=v"(d) : "v"(lo), "v"(hi));
    return d;
}

// ---------------- prep: W fp32 -> bf16 transposed wt[mat][col][k] ----------------
__global__ __launch_bounds__(256) void k_prep_w(const float* __restrict__ w0, const float* __restrict__ w1,
                                                const float* __restrict__ w2, const float* __restrict__ w3,
                                                unsigned short* __restrict__ wt) {
    int c = blockIdx.x, mat = blockIdx.y, k = threadIdx.x;
    const float* w = (mat == 0) ? w0 : (mat == 1) ? w1 : (mat == 2) ? w2 : w3;
    wt[((size_t)(mat * 256 + c)) * 256 + k] = f2bf(w[k * 256 + c]);
}

// ---------------- adjacency -> bitmask rows (streaming, forced MLP) ----------------
// mbg[row][kw]: bit j of word kw = (adj[row][32kw+j] != 0). Wave = one row.
__global__ __launch_bounds__(256) void k_mask(const int* __restrict__ adj,
                                              unsigned int* __restrict__ mbg) {
    int wave = (blockIdx.x * 256 + threadIdx.x) >> 6;   // 0..16383 = global row
    int lane = threadIdx.x & 63;
    int shamt = 4 * (lane & 7);
    int g8 = lane >> 3;
    const int4* p = reinterpret_cast<const int4*>(adj) + (size_t)wave * 512 + lane;
    unsigned int* outp = mbg + (size_t)wave * 64;

    int4 v[8];
#pragma unroll
    for (int i = 0; i < 8; ++i)
        v[i] = p[i * 64];
    __builtin_amdgcn_sched_barrier(0);

#pragma unroll
    for (int i = 0; i < 8; ++i) {
        unsigned int nib = (v[i].x != 0 ? 1u : 0u) | (v[i].y != 0 ? 2u : 0u)
                         | (v[i].z != 0 ? 4u : 0u) | (v[i].w != 0 ? 8u : 0u);
        unsigned int r = nib << shamt;
        r |= (unsigned int)__shfl_xor((int)r, 1, 64);
        r |= (unsigned int)__shfl_xor((int)r, 2, 64);
        r |= (unsigned int)__shfl_xor((int)r, 4, 64);
        if ((lane & 7) == 0) outp[i * 8 + g8] = r;
    }
}

// ---------------- bit-transpose bitmask: mbgT2[b][qt32][key'] ----------------
// Word at (b, qt32, key'(k)): bit q = adj[b][qt32*32+q][k]. key' interleaves
// (k, k+4) pairs within each 8-key group so k_attn's s_load_dwordx2 yields the
// (lo=keyA over q0..31, hi=keyB) 64-bit lane mask for one S^T element.
// Block = (b, 64-row group): coalesced load to LDS, 5-stage shfl_xor bit
// butterfly (32x32 per lane-half), permuted coalesced writes.
__global__ __launch_bounds__(256) void k_maskT2(const unsigned int* __restrict__ mbg,
                                                unsigned int* __restrict__ mbgT2) {
    __shared__ unsigned int bits[64][65];
    int tid = threadIdx.x, lane = tid & 63, wv = tid >> 6;
    int b = blockIdx.x >> 5, qg = blockIdx.x & 31;

    {
        int row = tid >> 2, cc = (tid & 3) * 16;
        const uint4* src = reinterpret_cast<const uint4*>(
            mbg + ((size_t)(b * N_ + qg * 64 + row)) * 64 + cc);
#pragma unroll
        for (int j = 0; j < 4; ++j) {
            uint4 v = src[j];
            bits[row][cc + 4 * j + 0] = v.x; bits[row][cc + 4 * j + 1] = v.y;
            bits[row][cc + 4 * j + 2] = v.z; bits[row][cc + 4 * j + 3] = v.w;
        }
    }
    __syncthreads();

    int h = lane >> 5, l31 = lane & 31;
    const unsigned int M[5] = {0x0000FFFFu, 0x00FF00FFu, 0x0F0F0F0Fu, 0x33333333u, 0x55555555u};
#pragma unroll
    for (int j = 0; j < 16; ++j) {
        int kw = wv * 16 + j;
        unsigned int w = bits[lane][kw];
#pragma unroll
        for (int si = 0; si < 5; ++si) {
            int s = 16 >> si;
            unsigned int m = M[si];
            unsigned int t = (unsigned int)__shfl_xor((int)w, s, 64);
            unsigned int a = (w & m) | ((t & m) << s);
            unsigned int c = (w & ~m) | ((t >> s) & m);
            w = (lane & s) ? c : a;
        }
        int k = kw * 32 + l31;
        int kp = (k & ~7) | ((k & 3) << 1) | ((k >> 2) & 1);
        mbgT2[((size_t)(b * 64 + qg * 2 + h)) * 2048 + kp] = w;
    }
}

// ---------------- fused QKV projection GEMM (single pass over x) ----------------
// Reads fp32 x ONCE (af reused for all 3 mats). Q row-major [bh][n][hd]
// (scaled); K row-major; V fragment-tile order.
__global__ __launch_bounds__(256) void k_qkv(const float* __restrict__ x,
                                             const unsigned short* __restrict__ wt,
                                             const float* __restrict__ bq, const float* __restrict__ bk,
                                             const float* __restrict__ bv,
                                             unsigned short* __restrict__ Qb, unsigned short* __restrict__ Kb,
                                             unsigned short* __restrict__ Vs) {
    int lane = threadIdx.x & 63;
    int wv = threadIdx.x >> 6;
    int row0 = blockIdx.x * 64 + wv * 16;
    int l15 = lane & 15, lg = lane >> 4;

    short8 af[8];
    const float* xrow = x + (size_t)(row0 + l15) * 256 + lg * 8;
#pragma unroll
    for (int kk = 0; kk < 8; ++kk) {
        float4 a = *reinterpret_cast<const float4*>(xrow + kk * 32);
        float4 b = *reinterpret_cast<const float4*>(xrow + kk * 32 + 4);
        union { short8 s8; unsigned int u[4]; } t;
        t.u[0] = cvtpk(a.x, a.y); t.u[1] = cvtpk(a.z, a.w);
        t.u[2] = cvtpk(b.x, b.y); t.u[3] = cvtpk(b.z, b.w);
        af[kk] = t.s8;
    }

    int b = row0 >> 11;            // 2048 rows per batch; 64-row blocks never cross
    int nbase = (row0 & 2047) + lg * 4;

#pragma unroll 1
    for (int mat = 0; mat < 3; ++mat) {
        const float* bias = (mat == 0) ? bq : (mat == 1) ? bk : bv;
        const float qs = (mat == 0) ? QSCALE : 1.0f;
        const unsigned short* wm = wt + (size_t)mat * 65536;
        for (int ci = 0; ci < 16; ++ci) {
            const unsigned short* wrow = wm + (size_t)(ci * 16 + l15) * 256 + lg * 8;
            f32x4 acc = {0.f, 0.f, 0.f, 0.f};
#pragma unroll
            for (int kk = 0; kk < 8; ++kk) {
                short8 bfg = *reinterpret_cast<const short8*>(wrow + kk * 32);
                acc = __builtin_amdgcn_mfma_f32_16x16x32_bf16(af[kk], bfg, acc, 0, 0, 0);
            }
            int col = ci * 16 + l15;
            float bcol = bias[col];
            int h = col >> 5, hd = col & 31;
            if (mat < 2) {
                unsigned short* dst = (mat == 0) ? Qb : Kb;
#pragma unroll
                for (int r = 0; r < 4; ++r) {
                    size_t off = ((size_t)(b * 8 + h) * 2048 + nbase + r) * 32 + hd;
                    dst[off] = f2bf((acc[r] + bcol) * qs);
                }
            } else {
                size_t off = (size_t)(b * 8 + h) * 65536
                           + ((size_t)(nbase >> 4) * 32 + hd) * 16 + (nbase & 15);
                ushort4 o;
                o.x = f2bf(acc[0] + bcol); o.y = f2bf(acc[1] + bcol);
                o.z = f2bf(acc[2] + bcol); o.w = f2bf(acc[3] + bcol);
                *reinterpret_cast<ushort4*>(Vs + off) = o;
            }
        }
    }
}

#define SL(j, offs) asm("s_load_dwordx2 %0, %1, " offs : "=s"(m##j) : "s"(mbase))
#define SLOAD16() do { \
    SL(0, "0x0");  SL(1, "0x8");  SL(2, "0x10"); SL(3, "0x18"); \
    SL(4, "0x20"); SL(5, "0x28"); SL(6, "0x30"); SL(7, "0x38"); \
    SL(8, "0x40"); SL(9, "0x48"); SL(10, "0x50"); SL(11, "0x58"); \
    SL(12, "0x60"); SL(13, "0x68"); SL(14, "0x70"); SL(15, "0x78"); } while (0)
#define CND(d, s_, mj) asm("v_cndmask_b32 %0, 0, %1, %2" : "=v"(d) : "v"(s_), "s"(mj))

// ---------------- masked attention (scalar-pipe lane masks) ----------------
// Barrier-free, LDS-free. blk: b = blk&7 (XCD), hg = (blk>>3)&1, qt32 = blk>>4;
// 4 waves = 4 heads, all sharing the same q-tile -> same scalar mask stream
// (K$ hits). Per 32-key tile: 4x 1KB K/V frag loads (vmcnt) + 16x
// s_load_dwordx2 64-bit lane masks (lgkmcnt, scalar pipe). Masking is ONE
// v_cndmask_b32 with s64 operand per element (lane = q matches mask bit).
// S^T = mfma(K,Q); cvt_pk + permlane32_swap -> PV B-frag; att^T += mfma(V,P);
// denominator via ones-MFMA.
__global__ __launch_bounds__(256, 6) void k_attn(const unsigned short* __restrict__ Qb,
                                                 const unsigned short* __restrict__ Kb,
                                                 const unsigned short* __restrict__ Vs,
                                                 const unsigned int* __restrict__ mbgT2,
                                                 unsigned short* __restrict__ att) {
    int tid = threadIdx.x;
    int lane = tid & 63;
    int l31 = lane & 31, hi = lane >> 5;
    int b = blockIdx.x & 7;
    int hg = (blockIdx.x >> 3) & 1;
    int qt32 = blockIdx.x >> 4;
    int q0 = qt32 * 32;
    int head = hg * 4 + (tid >> 6);
    int bh = b * 8 + head;

    const unsigned short* Qh = Qb + (size_t)bh * N_ * HD_;
    const unsigned short* Kh = Kb + (size_t)bh * N_ * HD_;
    const unsigned short* Vh = Vs + (size_t)bh * 65536;

    short8 qf0 = *reinterpret_cast<const short8*>(Qh + (size_t)(q0 + l31) * HD_ + hi * 8);
    short8 qf1 = *reinterpret_cast<const short8*>(Qh + (size_t)(q0 + l31) * HD_ + hi * 8 + 16);
    const unsigned short* krow = Kh + (size_t)l31 * HD_ + hi * 8;
    const unsigned short* vfp = Vh + (size_t)l31 * 16 + hi * 8;   // + tile*512

    unsigned long long mbase = (unsigned long long)(mbgT2 + (size_t)(b * 64 + qt32) * 2048);
    unsigned long long m0, m1, m2, m3, m4, m5, m6, m7, m8, m9, m10, m11, m12, m13, m14, m15;
    SLOAD16();   // tile 0 lane masks in flight

    const f32x16 fz = {0.f,0.f,0.f,0.f,0.f,0.f,0.f,0.f,0.f,0.f,0.f,0.f,0.f,0.f,0.f,0.f};
    const short8 onesf = {0x3F80, 0x3F80, 0x3F80, 0x3F80, 0x3F80, 0x3F80, 0x3F80, 0x3F80};
    f32x16 attacc = fz;
    f32x16 onesacc = fz;

#pragma unroll 2
    for (int t = 0; t < 64; ++t) {
        short8 kf0 = *reinterpret_cast<const short8*>(krow + (size_t)t * 1024);
        short8 kf1 = *reinterpret_cast<const short8*>(krow + (size_t)t * 1024 + 16);
        short8 vf0 = *reinterpret_cast<const short8*>(vfp + (size_t)t * 1024);
        short8 vf1 = *reinterpret_cast<const short8*>(vfp + (size_t)t * 1024 + 512);

        __builtin_amdgcn_s_setprio(1);
        f32x16 s = __builtin_amdgcn_mfma_f32_32x32x16_bf16(kf0, qf0, fz, 0, 0, 0);
        s = __builtin_amdgcn_mfma_f32_32x32x16_bf16(kf1, qf1, s, 0, 0, 0);
        __builtin_amdgcn_s_setprio(0);

        float e0 = exp2v(s[0]),  e1 = exp2v(s[1]),  e2 = exp2v(s[2]),  e3 = exp2v(s[3]);
        float e4 = exp2v(s[4]),  e5 = exp2v(s[5]),  e6 = exp2v(s[6]),  e7 = exp2v(s[7]);
        float e8 = exp2v(s[8]),  e9 = exp2v(s[9]),  e10 = exp2v(s[10]), e11 = exp2v(s[11]);
        float e12 = exp2v(s[12]), e13 = exp2v(s[13]), e14 = exp2v(s[14]), e15 = exp2v(s[15]);

        asm volatile("s_waitcnt lgkmcnt(0)"
                     : "+s"(m0), "+s"(m1), "+s"(m2), "+s"(m3), "+s"(m4), "+s"(m5), "+s"(m6), "+s"(m7),
                       "+s"(m8), "+s"(m9), "+s"(m10), "+s"(m11), "+s"(m12), "+s"(m13), "+s"(m14), "+s"(m15));

        float p0, p1, p2, p3, p4, p5, p6, p7, p8, p9, p10, p11, p12, p13, p14, p15;
        CND(p0, e0, m0);   CND(p1, e1, m1);   CND(p2, e2, m2);   CND(p3, e3, m3);
        CND(p4, e4, m4);   CND(p5, e5, m5);   CND(p6, e6, m6);   CND(p7, e7, m7);
        CND(p8, e8, m8);   CND(p9, e9, m9);   CND(p10, e10, m10); CND(p11, e11, m11);
        CND(p12, e12, m12); CND(p13, e13, m13); CND(p14, e14, m14); CND(p15, e15, m15);

        unsigned int pd[4][2];
        pd[0][0] = cvtpk(p0, p1);   pd[0][1] = cvtpk(p2, p3);
        pd[1][0] = cvtpk(p4, p5);   pd[1][1] = cvtpk(p6, p7);
        pd[2][0] = cvtpk(p8, p9);   pd[2][1] = cvtpk(p10, p11);
        pd[3][0] = cvtpk(p12, p13); pd[3][1] = cvtpk(p14, p15);

        mbase += 128;
        SLOAD16();   // next tile masks (t=63 reads pad)

        asm("v_permlane32_swap_b32 %0, %1" : "+v"(pd[0][0]), "+v"(pd[1][0]));
        asm("v_permlane32_swap_b32 %0, %1" : "+v"(pd[0][1]), "+v"(pd[1][1]));
        asm("v_permlane32_swap_b32 %0, %1" : "+v"(pd[2][0]), "+v"(pd[3][0]));
        asm("v_permlane32_swap_b32 %0, %1" : "+v"(pd[2][1]), "+v"(pd[3][1]));

        union { short8 s8; unsigned int u[4]; } bf0, bf1;
        bf0.u[0] = pd[0][0]; bf0.u[1] = pd[0][1]; bf0.u[2] = pd[1][0]; bf0.u[3] = pd[1][1];
        bf1.u[0] = pd[2][0]; bf1.u[1] = pd[2][1]; bf1.u[2] = pd[3][0]; bf1.u[3] = pd[3][1];

        __builtin_amdgcn_s_setprio(1);
        attacc = __builtin_amdgcn_mfma_f32_32x32x16_bf16(vf0, bf0.s8, attacc, 0, 0, 0);
        attacc = __builtin_amdgcn_mfma_f32_32x32x16_bf16(vf1, bf1.s8, attacc, 0, 0, 0);
        onesacc = __builtin_amdgcn_mfma_f32_32x32x16_bf16(onesf, bf0.s8, onesacc, 0, 0, 0);
        onesacc = __builtin_amdgcn_mfma_f32_32x32x16_bf16(onesf, bf1.s8, onesacc, 0, 0, 0);
        __builtin_amdgcn_s_setprio(0);
    }

    float rcp = 1.f / onesacc[0];   // every reg holds sum_k P[k][q=l31]

    unsigned short* arow = att + ((size_t)b * N_ + q0 + l31) * D_ + head * HD_;
#pragma unroll
    for (int g = 0; g < 4; ++g) {
        ushort4 o;
        o.x = f2bf(attacc[4 * g + 0] * rcp);
        o.y = f2bf(attacc[4 * g + 1] * rcp);
        o.z = f2bf(attacc[4 * g + 2] * rcp);
        o.w = f2bf(attacc[4 * g + 3] * rcp);
        *reinterpret_cast<ushort4*>(arow + 8 * g + 4 * hi) = o;
    }
}

// ---------------- out projection + residual + LayerNorm ----------------
__global__ __launch_bounds__(256) void k_outln(const unsigned short* __restrict__ att,
                                               const unsigned short* __restrict__ wot,
                                               const float* __restrict__ bo,
                                               const float* __restrict__ x,
                                               const float* __restrict__ gamma, const float* __restrict__ beta,
                                               float* __restrict__ out) {
    int lane = threadIdx.x & 63, wv = threadIdx.x >> 6;
    int l15 = lane & 15, lg = lane >> 4;
    int row0 = blockIdx.x * 64 + wv * 16;

    short8 af[8];
    const unsigned short* arow = att + (size_t)(row0 + l15) * 256 + lg * 8;
#pragma unroll
    for (int kk = 0; kk < 8; ++kk)
        af[kk] = *reinterpret_cast<const short8*>(arow + kk * 32);

    float v[16][4];
#pragma unroll
    for (int ci = 0; ci < 16; ++ci) {
        const unsigned short* wrow = wot + (size_t)(ci * 16 + l15) * 256 + lg * 8;
        f32x4 acc = {0.f, 0.f, 0.f, 0.f};
#pragma unroll
        for (int kk = 0; kk < 8; ++kk) {
            short8 bfg = *reinterpret_cast<const short8*>(wrow + kk * 32);
            acc = __builtin_amdgcn_mfma_f32_16x16x32_bf16(af[kk], bfg, acc, 0, 0, 0);
        }
        float bcol = bo[ci * 16 + l15];
#pragma unroll
        for (int r = 0; r < 4; ++r)
            v[ci][r] = acc[r] + bcol + x[(size_t)(row0 + lg * 4 + r) * 256 + ci * 16 + l15];
    }

    float sum[4] = {0.f, 0.f, 0.f, 0.f}, sq[4] = {0.f, 0.f, 0.f, 0.f};
#pragma unroll
    for (int ci = 0; ci < 16; ++ci)
#pragma unroll
        for (int r = 0; r < 4; ++r) {
            sum[r] += v[ci][r];
            sq[r] += v[ci][r] * v[ci][r];
        }
#pragma unroll
    for (int d = 1; d < 16; d <<= 1)
#pragma unroll
        for (int r = 0; r < 4; ++r) {
            sum[r] += __shfl_xor(sum[r], d, 64);
            sq[r] += __shfl_xor(sq[r], d, 64);
        }

    float mu[4], rs[4];
#pragma unroll
    for (int r = 0; r < 4; ++r) {
        mu[r] = sum[r] * (1.f / 256.f);
        float var = sq[r] * (1.f / 256.f) - mu[r] * mu[r];
        rs[r] = rsqrtf(var + LN_EPS);
    }

#pragma unroll
    for (int ci = 0; ci < 16; ++ci) {
        float g = gamma[ci * 16 + l15], be = beta[ci * 16 + l15];
#pragma unroll
        for (int r = 0; r < 4; ++r)
            out[(size_t)(row0 + lg * 4 + r) * 256 + ci * 16 + l15] = (v[ci][r] - mu[r]) * rs[r] * g + be;
    }
}

extern "C" void kernel_launch(void* const* d_in, const int* in_sizes, int n_in,
                              void* d_out, int out_size, void* d_ws, size_t ws_size,
                              hipStream_t stream) {
    (void)in_sizes; (void)n_in; (void)out_size; (void)ws_size;
    const float* x     = (const float*)d_in[0];
    const int*   adj   = (const int*)d_in[1];
    const float* Wq    = (const float*)d_in[2];
    const float* bq    = (const float*)d_in[3];
    const float* Wk    = (const float*)d_in[4];
    const float* bk    = (const float*)d_in[5];
    const float* Wv    = (const float*)d_in[6];
    const float* bv    = (const float*)d_in[7];
    const float* Wo    = (const float*)d_in[8];
    const float* bo    = (const float*)d_in[9];
    const float* gamma = (const float*)d_in[10];
    const float* beta  = (const float*)d_in[11];
    float* out = (float*)d_out;

    char* ws = (char*)d_ws;
    unsigned short* wt   = (unsigned short*)ws; ws += (size_t)4 * 256 * 256 * 2; // 0.5 MB
    unsigned short* Qb   = (unsigned short*)ws; ws += (size_t)B_ * H_ * N_ * HD_ * 2; // 8.4 MB
    unsigned short* Kb   = (unsigned short*)ws; ws += (size_t)B_ * H_ * N_ * HD_ * 2;
    unsigned short* Vs   = (unsigned short*)ws; ws += (size_t)B_ * H_ * N_ * HD_ * 2;
    unsigned short* att  = (unsigned short*)ws; ws += (size_t)16384 * 256 * 2;
    unsigned int*   mbg  = (unsigned int*)ws;   ws += (size_t)B_ * N_ * 64 * 4;  // 4.2 MB
    unsigned int*   mbgT2 = (unsigned int*)ws;  ws += (size_t)B_ * 64 * 2048 * 4 + 256; // 4.2 MB + pad

    k_prep_w<<<dim3(256, 4), 256, 0, stream>>>(Wq, Wk, Wv, Wo, wt);
    k_mask<<<4096, 256, 0, stream>>>(adj, mbg);
    k_maskT2<<<256, 256, 0, stream>>>(mbg, mbgT2);
    k_qkv<<<256, 256, 0, stream>>>(x, wt, bq, bk, bv, Qb, Kb, Vs);
    k_attn<<<1024, 256, 0, stream>>>(Qb, Kb, Vs, mbgT2, att);
    k_outln<<<256, 256, 0, stream>>>(att, wt + 3 * 65536, bo, x, gamma, beta, out);
}